// Round 20
// baseline (76.981 us; speedup 1.0000x reference)
//
#include <hip/hip_runtime.h>
#include <math.h>

#define S 512
#define NH 8
#define HD 64

typedef short short8 __attribute__((ext_vector_type(8)));
typedef float f32x4 __attribute__((ext_vector_type(4)));

__device__ __forceinline__ short bf16_hi(float x) {
  union { float f; unsigned u; } v; v.f = x;
  unsigned r = v.u + 0x7fffu + ((v.u >> 16) & 1u);
  return (short)(r >> 16);
}
__device__ __forceinline__ float bf16_val(short h) {
  union { float f; unsigned u; } v; v.u = ((unsigned)(unsigned short)h) << 16;
  return v.f;
}
__device__ __forceinline__ float softplus_f(float x) {
  return fmaxf(x, 0.f) + log1pf(__expf(-fabsf(x))) + 1e-4f;
}

// ---------------------------------------------------------------------------
// proj_gemm: z=0 -> Q (3-term split-bf16, rope/softplus -> interleaved qms)
//            z=1 -> K (3-term, transposed rope/softplus -> interleaved kmsT)
//            z=2 -> V (1-term, transposed bf16 VT[h*64+d][s] epilogue)
// fp32 inputs converted to (hi|lo) bf16 during LDS staging (no conv pass).
// qms[h][q][d][2] = {mu, sigma};  kmsT[h][d][s][2] = {mu, sigma}
// ---------------------------------------------------------------------------
__global__ __launch_bounds__(256) void proj_gemm(const float* __restrict__ X,
                                                 const float* __restrict__ wq,
                                                 const float* __restrict__ wk,
                                                 const float* __restrict__ wv,
                                                 const float* __restrict__ cosp,
                                                 const float* __restrict__ sinp,
                                                 float* __restrict__ qms,
                                                 float* __restrict__ kmsT,
                                                 short* __restrict__ VTg) {
  const int z = blockIdx.z;
  if (z == 2 && blockIdx.x >= 8) return;
  __shared__ __align__(16) char smem[52992];
  short (*Ah)[72] = (short(*)[72])(smem);
  short (*Al)[72] = (short(*)[72])(smem + 9216);
  short (*Bh)[72] = (short(*)[72])(smem + 18432);
  short (*Bl)[72] = (short(*)[72])(smem + 27648);
  float (*Cs)[69]  = (float(*)[69])(smem);            // epilogue reuse
  float (*CsC)[69] = (float(*)[69])(smem + 17664);    // cos tile (K path)
  float (*SsC)[69] = (float(*)[69])(smem + 35328);    // sin tile (K path)

  const float* Bsrc = (z == 0) ? wq : (z == 1) ? wk : wv;
  const int t = threadIdx.x;
  const int bm = blockIdx.y * 64, bn = blockIdx.x * 64;
  const int w = t >> 6, lane = t & 63;
  const int wr = (w >> 1) * 32, wc = (w & 1) * 32;
  const int fr = lane & 15, kg = (lane >> 4) << 3;
  const int r = t >> 2, c16 = (t & 3) << 4;
  f32x4 acc00 = {}, acc01 = {}, acc10 = {}, acc11 = {};

  for (int kt = 0; kt < 8; ++kt) {
    const int k0 = kt << 6;
    float4 av[4], bv[4];
#pragma unroll
    for (int i = 0; i < 4; ++i)
      av[i] = *(const float4*)(X + (size_t)(bm + r) * 512 + k0 + c16 + i * 4);
#pragma unroll
    for (int i = 0; i < 4; ++i)
      bv[i] = *(const float4*)(Bsrc + (size_t)(bn + r) * 512 + k0 + c16 + i * 4);
    __syncthreads();  // previous step's fragment reads done
#pragma unroll
    for (int i = 0; i < 4; ++i) {
      float fa[4] = {av[i].x, av[i].y, av[i].z, av[i].w};
      float fb[4] = {bv[i].x, bv[i].y, bv[i].z, bv[i].w};
      short ha[4], la[4], hb[4], lb[4];
#pragma unroll
      for (int j = 0; j < 4; ++j) {
        ha[j] = bf16_hi(fa[j]); la[j] = bf16_hi(fa[j] - bf16_val(ha[j]));
        hb[j] = bf16_hi(fb[j]); lb[j] = bf16_hi(fb[j] - bf16_val(hb[j]));
      }
      *(short4*)&Ah[r][c16 + i * 4] = make_short4(ha[0], ha[1], ha[2], ha[3]);
      *(short4*)&Bh[r][c16 + i * 4] = make_short4(hb[0], hb[1], hb[2], hb[3]);
      if (z < 2) {
        *(short4*)&Al[r][c16 + i * 4] = make_short4(la[0], la[1], la[2], la[3]);
        *(short4*)&Bl[r][c16 + i * 4] = make_short4(lb[0], lb[1], lb[2], lb[3]);
      }
    }
    __syncthreads();
#pragma unroll
    for (int ks = 0; ks < 64; ks += 32) {
      short8 ah0f = *(const short8*)&Ah[wr + fr][ks + kg];
      short8 ah1f = *(const short8*)&Ah[wr + 16 + fr][ks + kg];
      short8 bh0f = *(const short8*)&Bh[wc + fr][ks + kg];
      short8 bh1f = *(const short8*)&Bh[wc + 16 + fr][ks + kg];
      acc00 = __builtin_amdgcn_mfma_f32_16x16x32_bf16(ah0f, bh0f, acc00, 0, 0, 0);
      acc01 = __builtin_amdgcn_mfma_f32_16x16x32_bf16(ah0f, bh1f, acc01, 0, 0, 0);
      acc10 = __builtin_amdgcn_mfma_f32_16x16x32_bf16(ah1f, bh0f, acc10, 0, 0, 0);
      acc11 = __builtin_amdgcn_mfma_f32_16x16x32_bf16(ah1f, bh1f, acc11, 0, 0, 0);
      if (z < 2) {
        short8 al0f = *(const short8*)&Al[wr + fr][ks + kg];
        short8 al1f = *(const short8*)&Al[wr + 16 + fr][ks + kg];
        short8 bl0f = *(const short8*)&Bl[wc + fr][ks + kg];
        short8 bl1f = *(const short8*)&Bl[wc + 16 + fr][ks + kg];
        acc00 = __builtin_amdgcn_mfma_f32_16x16x32_bf16(al0f, bh0f, acc00, 0, 0, 0);
        acc01 = __builtin_amdgcn_mfma_f32_16x16x32_bf16(al0f, bh1f, acc01, 0, 0, 0);
        acc10 = __builtin_amdgcn_mfma_f32_16x16x32_bf16(al1f, bh0f, acc10, 0, 0, 0);
        acc11 = __builtin_amdgcn_mfma_f32_16x16x32_bf16(al1f, bh1f, acc11, 0, 0, 0);
        acc00 = __builtin_amdgcn_mfma_f32_16x16x32_bf16(ah0f, bl0f, acc00, 0, 0, 0);
        acc01 = __builtin_amdgcn_mfma_f32_16x16x32_bf16(ah0f, bl1f, acc01, 0, 0, 0);
        acc10 = __builtin_amdgcn_mfma_f32_16x16x32_bf16(ah1f, bl0f, acc10, 0, 0, 0);
        acc11 = __builtin_amdgcn_mfma_f32_16x16x32_bf16(ah1f, bl1f, acc11, 0, 0, 0);
      }
    }
  }

  const int orow = (lane >> 4) << 2;
  // ---- epilogue: stage C tile in LDS ----
  __syncthreads();  // all fragment reads of staging LDS done
#pragma unroll
  for (int j = 0; j < 4; ++j) {
    Cs[wr + orow + j][wc + fr] = acc00[j];
    Cs[wr + orow + j][wc + 16 + fr] = acc01[j];
    Cs[wr + 16 + orow + j][wc + fr] = acc10[j];
    Cs[wr + 16 + orow + j][wc + 16 + fr] = acc11[j];
  }
  const int h = bn >> 7;
  const int issig = (bn >> 6) & 1;
  if (z == 1 && !issig) {  // stage cos/sin tiles for transposed reads
#pragma unroll
    for (int i = 0; i < 16; ++i) {
      int rr = (i << 2) + w;
      CsC[rr][lane] = cosp[(size_t)(bm + rr) * 64 + lane];
      SsC[rr][lane] = sinp[(size_t)(bm + rr) * 64 + lane];
    }
  }
  __syncthreads();

  if (z == 2) {  // V out: transposed bf16 VT[(bn+d)][s]
#pragma unroll
    for (int i = 0; i < 16; ++i) {
      int d = (i << 2) + w, sl = lane;
      VTg[(size_t)(bn + d) * 512 + bm + sl] = bf16_hi(Cs[sl][d]);
    }
    return;
  }
  if (z == 0) {  // Q out: interleaved qms[h][q][d][2]
#pragma unroll
    for (int i = 0; i < 16; ++i) {
      int rr = (i << 2) + w, d = lane, s = bm + rr;
      float c = Cs[rr][d];
      float v;
      if (!issig) {
        float p = Cs[rr][d ^ 32];
        float rot = (d < 32) ? -p : p;
        v = c * cosp[(size_t)s * 64 + d] + rot * sinp[(size_t)s * 64 + d];
      } else {
        v = softplus_f(c);
      }
      qms[(size_t)((h << 9) + s) * 128 + (d << 1) + issig] = v;
    }
  } else {  // K out: interleaved transposed kmsT[h][d][s][2]
#pragma unroll
    for (int i = 0; i < 16; ++i) {
      int d = (i << 2) + w, sl = lane;
      float c = Cs[sl][d];
      float v;
      if (!issig) {
        float p = Cs[sl][d ^ 32];
        float rot = (d < 32) ? -p : p;
        v = c * CsC[sl][d] + rot * SsC[sl][d];
      } else {
        v = softplus_f(c);
      }
      kmsT[(size_t)((h << 6) + d) * 1024 + ((bm + sl) << 1) + issig] = v;
    }
  }
}

// ---------- W2 scores, split-D: K direct from global (no LDS, no barrier) ----
// Interleaved kmsT -> lane reads one coalesced float2 per d-row (512B/wave).
// Depth-1 register prefetch across d0 steps; Q via wave-uniform SMEM.
// Oct-rcp + single deferred log: 4 rcp + 1 log per (q, 32d).
__global__ __launch_bounds__(256) void scores_kernel(const float* __restrict__ qms,
                                                     const float* __restrict__ kmsT,
                                                     float* __restrict__ SCa,
                                                     float* __restrict__ SCb) {
  const int kt = blockIdx.x >> 1, half = blockIdx.x & 1;
  const int qt = blockIdx.y, h = blockIdx.z;
  const int q0 = qt * 16, k0 = kt * 64;
  if (k0 > q0 + 15) return;  // fully masked tile
  float* __restrict__ SC = half ? SCb : SCa;
  const int dbase = half << 5;
  const int t = threadIdx.x, lane = t & 63;
  const int qb = __builtin_amdgcn_readfirstlane((t >> 6) << 2);  // wave's 4 q rows
  const float* __restrict__ qp = qms + (size_t)((h << 9) + q0 + qb) * 128 + (dbase << 1);
  // K: lane-coalesced float2 per d-row; row stride 512 float2 (1024 floats)
  const float2* __restrict__ kp =
      (const float2*)(kmsT + (size_t)((h << 6) + dbase) * 1024 + (k0 << 1)) + lane;
  float wd[4] = {}, pr[4] = {1.f, 1.f, 1.f, 1.f};
  float2 kk[8], kkn[8];
#pragma unroll
  for (int dd = 0; dd < 8; ++dd)
    kk[dd] = kp[(size_t)dd * 512];
  for (int d0 = 0; d0 < 32; d0 += 8) {
    const bool more = (d0 < 24);
    if (more) {
#pragma unroll
      for (int dd = 0; dd < 8; ++dd)
        kkn[dd] = kp[(size_t)(d0 + 8 + dd) * 512];
    }
#pragma unroll
    for (int qi = 0; qi < 4; ++qi) {
      float qv[16];
      const float* qq = qp + qi * 128 + (d0 << 1);
#pragma unroll
      for (int j = 0; j < 4; ++j)
        *(float4*)&qv[j * 4] = *(const float4*)(qq + j * 4);
      float s0 = qv[1]  + kk[0].y, s1 = qv[3]  + kk[1].y;
      float s2 = qv[5]  + kk[2].y, s3 = qv[7]  + kk[3].y;
      float s4 = qv[9]  + kk[4].y, s5 = qv[11] + kk[5].y;
      float s6 = qv[13] + kk[6].y, s7 = qv[15] + kk[7].y;
      float e0 = qv[0]  - kk[0].x, e1 = qv[2]  - kk[1].x;
      float e2 = qv[4]  - kk[2].x, e3 = qv[6]  - kk[3].x;
      float e4 = qv[8]  - kk[4].x, e5 = qv[10] - kk[5].x;
      float e6 = qv[12] - kk[6].x, e7 = qv[14] - kk[7].x;
      float s01 = s0 * s1, s23 = s2 * s3, s45 = s4 * s5, s67 = s6 * s7;
      float s0123 = s01 * s23, s4567 = s45 * s67;
      float oct = s0123 * s4567;
      float n01 = fmaf(e0 * e0, s1, e1 * e1 * s0);
      float n23 = fmaf(e2 * e2, s3, e3 * e3 * s2);
      float n45 = fmaf(e4 * e4, s5, e5 * e5 * s4);
      float n67 = fmaf(e6 * e6, s7, e7 * e7 * s6);
      float n0123 = fmaf(n01, s23, n23 * s01);
      float n4567 = fmaf(n45, s67, n67 * s45);
      float num = fmaf(n0123, s4567, n4567 * s0123);
      wd[qi] = fmaf(num, __builtin_amdgcn_rcpf(oct), wd[qi]);
      pr[qi] *= oct;  // deferred log: one v_log_f32 per (q,32d) at the end
    }
    if (more) {
#pragma unroll
      for (int dd = 0; dd < 8; ++dd) kk[dd] = kkn[dd];
    }
  }
  const int k = k0 + lane;
#pragma unroll
  for (int qi = 0; qi < 4; ++qi) {
    int q = q0 + qb + qi;
    SC[(size_t)((h << 9) + q) * 512 + k] =
        -0.5f * (wd[qi] + 0.6931471805599453f * __log2f(pr[qi]));  // partial
  }
}

// ---------- softmax + MFMA PV: paired 8-row groups (p, 63-p) -----------------
__global__ __launch_bounds__(256) void softpv_kernel(const float* __restrict__ SCa,
                                                     const float* __restrict__ SCb,
                                                     const short* __restrict__ VTg,
                                                     short* __restrict__ attn2) {
  const int p = blockIdx.x;       // 0..31
  const int h = blockIdx.y;
  const int g0 = p, g1 = 63 - p;  // 8-row groups
  const int nj0 = (g0 >> 3) + 1;  // causal k-tile count (uniform within group)
  const int nj1 = (g1 >> 3) + 1;
  const int t = threadIdx.x, w = t >> 6, lane = t & 63;
  __shared__ __align__(16) short P2[16][520];   // p bf16, rows 0-7 g0, 8-15 g1
  __shared__ __align__(16) short VT_s[64][72];  // V^T tile [d][k]
  __shared__ float inv_s[16];
#pragma unroll
  for (int gi = 0; gi < 2; ++gi) {
    const int g = gi ? g1 : g0;
    const int nj = gi ? nj1 : nj0;
#pragma unroll
    for (int r = 0; r < 2; ++r) {
      const int row = gi * 8 + w * 2 + r;
      const int q = g * 8 + w * 2 + r;
      float rv[8];
      float m = -3.4e38f;
#pragma unroll
      for (int j = 0; j < 8; ++j)
        if (j < nj) {
          size_t off = (size_t)((h << 9) + q) * 512 + j * 64 + lane;
          float sc = SCa[off] + SCb[off];
          if (j * 64 + lane > q) sc = -1e9f;  // causal mask
          rv[j] = sc;
          m = fmaxf(m, sc);
        }
#pragma unroll
      for (int off = 32; off; off >>= 1) m = fmaxf(m, __shfl_xor(m, off));
      float sum = 0.f;
#pragma unroll
      for (int j = 0; j < 8; ++j) {
        if (j < nj) {
          float pv = __expf(rv[j] - m);
          sum += pv;
          P2[row][j * 64 + lane] = bf16_hi(pv);
        } else if (j < nj1) {
          P2[row][j * 64 + lane] = 0;  // masked tiles of g0 rows
        }
      }
#pragma unroll
      for (int off = 32; off; off >>= 1) sum += __shfl_xor(sum, off);
      if (lane == 0) inv_s[row] = 1.0f / sum;
    }
  }
  // PV: wave w owns output cols [w*16, w*16+16); K loop over nj1 tiles.
  const int fr = lane & 15, kg = (lane >> 4) << 3;
  f32x4 acc = {};
  for (int kt = 0; kt < nj1; ++kt) {
    __syncthreads();  // P2 complete (kt==0) / previous VT_s reads done
    {  // stage VT tile [d][k] bf16 (contiguous rows from VTg)
      int d = t >> 2, i = (t & 3) << 4;
      const short* src = VTg + (size_t)((h << 6) + d) * 512 + (kt << 6) + i;
      *(short8*)&VT_s[d][i] = *(const short8*)src;
      *(short8*)&VT_s[d][i + 8] = *(const short8*)(src + 8);
    }
    __syncthreads();
#pragma unroll
    for (int ks = 0; ks < 64; ks += 32) {
      short8 a = *(const short8*)&P2[fr][(kt << 6) + ks + kg];
      short8 b = *(const short8*)&VT_s[(w << 4) + fr][ks + kg];
      acc = __builtin_amdgcn_mfma_f32_16x16x32_bf16(a, b, acc, 0, 0, 0);
    }
  }
  const int orow = (lane >> 4) << 2;
#pragma unroll
  for (int j = 0; j < 4; ++j) {
    int row = orow + j;
    int q = (row < 8) ? g0 * 8 + row : g1 * 8 + (row - 8);
    attn2[(size_t)q * 512 + (h << 6) + (w << 4) + fr] = bf16_hi(acc[j] * inv_s[row]);
  }
}

// ---------- O projection: out = attn2(bf16) · wo^T, wo converted in staging --
__global__ __launch_bounds__(256) void gemm_o(const short* __restrict__ A2,
                                              const float* __restrict__ wo,
                                              float* __restrict__ out) {
  __shared__ __align__(16) short Ah[64][72];
  __shared__ __align__(16) short Bh[64][72];
  const int t = threadIdx.x;
  const int bm = blockIdx.y * 64, bn = blockIdx.x * 64;
  const int w = t >> 6, lane = t & 63;
  const int wr = (w >> 1) * 32, wc = (w & 1) * 32;
  const int fr = lane & 15, kg = (lane >> 4) << 3;
  const int r = t >> 2, c16 = (t & 3) << 4;
  f32x4 acc00 = {}, acc01 = {}, acc10 = {}, acc11 = {};
  for (int kt = 0; kt < 8; ++kt) {
    const int k0 = kt << 6;
    short8 a0 = *(const short8*)(A2 + (size_t)(bm + r) * 512 + k0 + c16);
    short8 a1 = *(const short8*)(A2 + (size_t)(bm + r) * 512 + k0 + c16 + 8);
    float4 bv[4];
#pragma unroll
    for (int i = 0; i < 4; ++i)
      bv[i] = *(const float4*)(wo + (size_t)(bn + r) * 512 + k0 + c16 + i * 4);
    __syncthreads();
    *(short8*)&Ah[r][c16] = a0;
    *(short8*)&Ah[r][c16 + 8] = a1;
#pragma unroll
    for (int i = 0; i < 4; ++i) {
      float fb[4] = {bv[i].x, bv[i].y, bv[i].z, bv[i].w};
      *(short4*)&Bh[r][c16 + i * 4] =
          make_short4(bf16_hi(fb[0]), bf16_hi(fb[1]), bf16_hi(fb[2]), bf16_hi(fb[3]));
    }
    __syncthreads();
#pragma unroll
    for (int ks = 0; ks < 64; ks += 32) {
      short8 af0 = *(const short8*)&Ah[wr + fr][ks + kg];
      short8 af1 = *(const short8*)&Ah[wr + 16 + fr][ks + kg];
      short8 bf0 = *(const short8*)&Bh[wc + fr][ks + kg];
      short8 bf1 = *(const short8*)&Bh[wc + 16 + fr][ks + kg];
      acc00 = __builtin_amdgcn_mfma_f32_16x16x32_bf16(af0, bf0, acc00, 0, 0, 0);
      acc01 = __builtin_amdgcn_mfma_f32_16x16x32_bf16(af0, bf1, acc01, 0, 0, 0);
      acc10 = __builtin_amdgcn_mfma_f32_16x16x32_bf16(af1, bf0, acc10, 0, 0, 0);
      acc11 = __builtin_amdgcn_mfma_f32_16x16x32_bf16(af1, bf1, acc11, 0, 0, 0);
    }
  }
  const int orow = (lane >> 4) << 2;
#pragma unroll
  for (int j = 0; j < 4; ++j) {
    out[(size_t)(bm + wr + orow + j) * 512 + bn + wc + fr] = acc00[j];
    out[(size_t)(bm + wr + orow + j) * 512 + bn + wc + 16 + fr] = acc01[j];
    out[(size_t)(bm + wr + 16 + orow + j) * 512 + bn + wc + fr] = acc10[j];
    out[(size_t)(bm + wr + 16 + orow + j) * 512 + bn + wc + 16 + fr] = acc11[j];
  }
}

// ------------------------------------------------------------------------------
extern "C" void kernel_launch(void* const* d_in, const int* in_sizes, int n_in,
                              void* d_out, int out_size, void* d_ws, size_t ws_size,
                              hipStream_t stream) {
  const float* X    = (const float*)d_in[0];
  const float* cosp = (const float*)d_in[1];
  const float* sinp = (const float*)d_in[2];
  // d_in[3] = attention_mask (recomputed inline: exact causal 0/-1e9)
  const float* wq   = (const float*)d_in[4];
  const float* wk   = (const float*)d_in[5];
  const float* wv   = (const float*)d_in[6];
  const float* wo   = (const float*)d_in[7];
  float* out = (float*)d_out;

  uint8_t* W = (uint8_t*)d_ws;
  const size_t MB = 1u << 20;
  float* qms   = (float*)(W + 0 * MB);   // [8][512][64][2] 2MB interleaved
  float* kmsT  = (float*)(W + 2 * MB);   // [8][64][512][2] 2MB interleaved
  short* VTg   = (short*)(W + 4 * MB);   // [512 hd][512 s] bf16 0.5MB
  short* attn2 = (short*)(W + 5 * MB);   // [512][512] bf16 0.5MB
  float* SCa   = (float*)(W + 6 * MB);   // [8][512][512] 8MB (d 0..31 partial)
  float* SCb   = (float*)(W + 14 * MB);  // [8][512][512] 8MB (d 32..63 partial)

  proj_gemm<<<dim3(16, 8, 3), 256, 0, stream>>>(X, wq, wk, wv, cosp, sinp,
                                                qms, kmsT, VTg);
  scores_kernel<<<dim3(16, 32, 8), 256, 0, stream>>>(qms, kmsT, SCa, SCb);
  softpv_kernel<<<dim3(32, 8), 256, 0, stream>>>(SCa, SCb, VTg, attn2);
  gemm_o<<<dim3(8, 8), 256, 0, stream>>>(attn2, wo, out);
}

// Round 21
// 66.014 us; speedup vs baseline: 1.1661x; 1.1661x over previous
//
#include <hip/hip_runtime.h>
#include <math.h>

#define S 512
#define NH 8
#define HD 64

typedef short short8 __attribute__((ext_vector_type(8)));
typedef float f32x4 __attribute__((ext_vector_type(4)));

__device__ __forceinline__ short bf16_hi(float x) {
  union { float f; unsigned u; } v; v.f = x;
  unsigned r = v.u + 0x7fffu + ((v.u >> 16) & 1u);
  return (short)(r >> 16);
}
__device__ __forceinline__ float bf16_val(short h) {
  union { float f; unsigned u; } v; v.u = ((unsigned)(unsigned short)h) << 16;
  return v.f;
}
__device__ __forceinline__ float softplus_f(float x) {
  return fmaxf(x, 0.f) + log1pf(__expf(-fabsf(x))) + 1e-4f;
}

// ---------------------------------------------------------------------------
// proj_gemm: z=0 -> Q (3-term split-bf16, rope/softplus -> interleaved qms)
//            z=1 -> K (3-term, transposed rope/softplus -> interleaved kmsT)
//            z=2 -> V (1-term, transposed bf16 VT[h*64+d][s] epilogue)
// fp32 inputs converted to (hi|lo) bf16 during LDS staging (no conv pass).
// qms[h][q][d][2] = {mu, sigma};  kmsT[h][d][s][2] = {mu, sigma}
// ---------------------------------------------------------------------------
__global__ __launch_bounds__(256) void proj_gemm(const float* __restrict__ X,
                                                 const float* __restrict__ wq,
                                                 const float* __restrict__ wk,
                                                 const float* __restrict__ wv,
                                                 const float* __restrict__ cosp,
                                                 const float* __restrict__ sinp,
                                                 float* __restrict__ qms,
                                                 float* __restrict__ kmsT,
                                                 short* __restrict__ VTg) {
  const int z = blockIdx.z;
  if (z == 2 && blockIdx.x >= 8) return;
  __shared__ __align__(16) char smem[52992];
  short (*Ah)[72] = (short(*)[72])(smem);
  short (*Al)[72] = (short(*)[72])(smem + 9216);
  short (*Bh)[72] = (short(*)[72])(smem + 18432);
  short (*Bl)[72] = (short(*)[72])(smem + 27648);
  float (*Cs)[69]  = (float(*)[69])(smem);            // epilogue reuse
  float (*CsC)[69] = (float(*)[69])(smem + 17664);    // cos tile (K path)
  float (*SsC)[69] = (float(*)[69])(smem + 35328);    // sin tile (K path)

  const float* Bsrc = (z == 0) ? wq : (z == 1) ? wk : wv;
  const int t = threadIdx.x;
  const int bm = blockIdx.y * 64, bn = blockIdx.x * 64;
  const int w = t >> 6, lane = t & 63;
  const int wr = (w >> 1) * 32, wc = (w & 1) * 32;
  const int fr = lane & 15, kg = (lane >> 4) << 3;
  const int r = t >> 2, c16 = (t & 3) << 4;
  f32x4 acc00 = {}, acc01 = {}, acc10 = {}, acc11 = {};

  for (int kt = 0; kt < 8; ++kt) {
    const int k0 = kt << 6;
    float4 av[4], bv[4];
#pragma unroll
    for (int i = 0; i < 4; ++i)
      av[i] = *(const float4*)(X + (size_t)(bm + r) * 512 + k0 + c16 + i * 4);
#pragma unroll
    for (int i = 0; i < 4; ++i)
      bv[i] = *(const float4*)(Bsrc + (size_t)(bn + r) * 512 + k0 + c16 + i * 4);
    __syncthreads();  // previous step's fragment reads done
#pragma unroll
    for (int i = 0; i < 4; ++i) {
      float fa[4] = {av[i].x, av[i].y, av[i].z, av[i].w};
      float fb[4] = {bv[i].x, bv[i].y, bv[i].z, bv[i].w};
      short ha[4], la[4], hb[4], lb[4];
#pragma unroll
      for (int j = 0; j < 4; ++j) {
        ha[j] = bf16_hi(fa[j]); la[j] = bf16_hi(fa[j] - bf16_val(ha[j]));
        hb[j] = bf16_hi(fb[j]); lb[j] = bf16_hi(fb[j] - bf16_val(hb[j]));
      }
      *(short4*)&Ah[r][c16 + i * 4] = make_short4(ha[0], ha[1], ha[2], ha[3]);
      *(short4*)&Bh[r][c16 + i * 4] = make_short4(hb[0], hb[1], hb[2], hb[3]);
      if (z < 2) {
        *(short4*)&Al[r][c16 + i * 4] = make_short4(la[0], la[1], la[2], la[3]);
        *(short4*)&Bl[r][c16 + i * 4] = make_short4(lb[0], lb[1], lb[2], lb[3]);
      }
    }
    __syncthreads();
#pragma unroll
    for (int ks = 0; ks < 64; ks += 32) {
      short8 ah0f = *(const short8*)&Ah[wr + fr][ks + kg];
      short8 ah1f = *(const short8*)&Ah[wr + 16 + fr][ks + kg];
      short8 bh0f = *(const short8*)&Bh[wc + fr][ks + kg];
      short8 bh1f = *(const short8*)&Bh[wc + 16 + fr][ks + kg];
      acc00 = __builtin_amdgcn_mfma_f32_16x16x32_bf16(ah0f, bh0f, acc00, 0, 0, 0);
      acc01 = __builtin_amdgcn_mfma_f32_16x16x32_bf16(ah0f, bh1f, acc01, 0, 0, 0);
      acc10 = __builtin_amdgcn_mfma_f32_16x16x32_bf16(ah1f, bh0f, acc10, 0, 0, 0);
      acc11 = __builtin_amdgcn_mfma_f32_16x16x32_bf16(ah1f, bh1f, acc11, 0, 0, 0);
      if (z < 2) {
        short8 al0f = *(const short8*)&Al[wr + fr][ks + kg];
        short8 al1f = *(const short8*)&Al[wr + 16 + fr][ks + kg];
        short8 bl0f = *(const short8*)&Bl[wc + fr][ks + kg];
        short8 bl1f = *(const short8*)&Bl[wc + 16 + fr][ks + kg];
        acc00 = __builtin_amdgcn_mfma_f32_16x16x32_bf16(al0f, bh0f, acc00, 0, 0, 0);
        acc01 = __builtin_amdgcn_mfma_f32_16x16x32_bf16(al0f, bh1f, acc01, 0, 0, 0);
        acc10 = __builtin_amdgcn_mfma_f32_16x16x32_bf16(al1f, bh0f, acc10, 0, 0, 0);
        acc11 = __builtin_amdgcn_mfma_f32_16x16x32_bf16(al1f, bh1f, acc11, 0, 0, 0);
        acc00 = __builtin_amdgcn_mfma_f32_16x16x32_bf16(ah0f, bl0f, acc00, 0, 0, 0);
        acc01 = __builtin_amdgcn_mfma_f32_16x16x32_bf16(ah0f, bl1f, acc01, 0, 0, 0);
        acc10 = __builtin_amdgcn_mfma_f32_16x16x32_bf16(ah1f, bl0f, acc10, 0, 0, 0);
        acc11 = __builtin_amdgcn_mfma_f32_16x16x32_bf16(ah1f, bl1f, acc11, 0, 0, 0);
      }
    }
  }

  const int orow = (lane >> 4) << 2;
  // ---- epilogue: stage C tile in LDS ----
  __syncthreads();  // all fragment reads of staging LDS done
#pragma unroll
  for (int j = 0; j < 4; ++j) {
    Cs[wr + orow + j][wc + fr] = acc00[j];
    Cs[wr + orow + j][wc + 16 + fr] = acc01[j];
    Cs[wr + 16 + orow + j][wc + fr] = acc10[j];
    Cs[wr + 16 + orow + j][wc + 16 + fr] = acc11[j];
  }
  const int h = bn >> 7;
  const int issig = (bn >> 6) & 1;
  if (z == 1 && !issig) {  // stage cos/sin tiles for transposed reads
#pragma unroll
    for (int i = 0; i < 16; ++i) {
      int rr = (i << 2) + w;
      CsC[rr][lane] = cosp[(size_t)(bm + rr) * 64 + lane];
      SsC[rr][lane] = sinp[(size_t)(bm + rr) * 64 + lane];
    }
  }
  __syncthreads();

  if (z == 2) {  // V out: transposed bf16 VT[(bn+d)][s]
#pragma unroll
    for (int i = 0; i < 16; ++i) {
      int d = (i << 2) + w, sl = lane;
      VTg[(size_t)(bn + d) * 512 + bm + sl] = bf16_hi(Cs[sl][d]);
    }
    return;
  }
  if (z == 0) {  // Q out: interleaved qms[h][q][d][2]
#pragma unroll
    for (int i = 0; i < 16; ++i) {
      int rr = (i << 2) + w, d = lane, s = bm + rr;
      float c = Cs[rr][d];
      float v;
      if (!issig) {
        float p = Cs[rr][d ^ 32];
        float rot = (d < 32) ? -p : p;
        v = c * cosp[(size_t)s * 64 + d] + rot * sinp[(size_t)s * 64 + d];
      } else {
        v = softplus_f(c);
      }
      qms[(size_t)((h << 9) + s) * 128 + (d << 1) + issig] = v;
    }
  } else {  // K out: interleaved transposed kmsT[h][d][s][2]
#pragma unroll
    for (int i = 0; i < 16; ++i) {
      int d = (i << 2) + w, sl = lane;
      float c = Cs[sl][d];
      float v;
      if (!issig) {
        float p = Cs[sl][d ^ 32];
        float rot = (d < 32) ? -p : p;
        v = c * CsC[sl][d] + rot * SsC[sl][d];
      } else {
        v = softplus_f(c);
      }
      kmsT[(size_t)((h << 6) + d) * 1024 + ((bm + sl) << 1) + issig] = v;
    }
  }
}

// ---------- W2 scores, split-D, oct-rcp + single deferred log (R19 proven) ---
__global__ __launch_bounds__(256) void scores_kernel(const float* __restrict__ qms,
                                                     const float* __restrict__ kmsT,
                                                     float* __restrict__ SCa,
                                                     float* __restrict__ SCb) {
  const int kt = blockIdx.x >> 1, half = blockIdx.x & 1;
  const int qt = blockIdx.y, h = blockIdx.z;
  const int q0 = qt * 16, k0 = kt * 64;
  if (k0 > q0 + 15) return;  // fully masked tile
  float* __restrict__ SC = half ? SCb : SCa;
  const int dbase = half << 5;
  __shared__ __align__(16) float K_s[32][132];  // [d][2k interleaved], pad 4
  const int t = threadIdx.x, lane = t & 63;
  {  // stage 32 d-rows x 128 floats (64 k's interleaved mu/sig)
    int d = t >> 3, i = t & 7;
    const float* src = kmsT + (size_t)((h << 6) + dbase + d) * 1024 + (k0 << 1) + i * 16;
    float* dst = &K_s[d][i * 16];
#pragma unroll
    for (int j = 0; j < 4; ++j)
      *(float4*)(dst + j * 4) = *(const float4*)(src + j * 4);
  }
  __syncthreads();
  const int qb = __builtin_amdgcn_readfirstlane((t >> 6) << 2);  // wave's 4 q rows
  const float* __restrict__ qp = qms + (size_t)((h << 9) + q0 + qb) * 128 + (dbase << 1);
  float wd[4] = {}, pr[4] = {1.f, 1.f, 1.f, 1.f};
  float2 kk[8], kkn[8];
#pragma unroll
  for (int dd = 0; dd < 8; ++dd)
    kk[dd] = *(const float2*)&K_s[dd][lane << 1];
  for (int d0 = 0; d0 < 32; d0 += 8) {
    const bool more = (d0 < 24);
    if (more) {
#pragma unroll
      for (int dd = 0; dd < 8; ++dd)
        kkn[dd] = *(const float2*)&K_s[d0 + 8 + dd][lane << 1];
    }
#pragma unroll
    for (int qi = 0; qi < 4; ++qi) {
      float qv[16];
      const float* qq = qp + qi * 128 + (d0 << 1);
#pragma unroll
      for (int j = 0; j < 4; ++j)
        *(float4*)&qv[j * 4] = *(const float4*)(qq + j * 4);
      float s0 = qv[1]  + kk[0].y, s1 = qv[3]  + kk[1].y;
      float s2 = qv[5]  + kk[2].y, s3 = qv[7]  + kk[3].y;
      float s4 = qv[9]  + kk[4].y, s5 = qv[11] + kk[5].y;
      float s6 = qv[13] + kk[6].y, s7 = qv[15] + kk[7].y;
      float e0 = qv[0]  - kk[0].x, e1 = qv[2]  - kk[1].x;
      float e2 = qv[4]  - kk[2].x, e3 = qv[6]  - kk[3].x;
      float e4 = qv[8]  - kk[4].x, e5 = qv[10] - kk[5].x;
      float e6 = qv[12] - kk[6].x, e7 = qv[14] - kk[7].x;
      float s01 = s0 * s1, s23 = s2 * s3, s45 = s4 * s5, s67 = s6 * s7;
      float s0123 = s01 * s23, s4567 = s45 * s67;
      float oct = s0123 * s4567;
      float n01 = fmaf(e0 * e0, s1, e1 * e1 * s0);
      float n23 = fmaf(e2 * e2, s3, e3 * e3 * s2);
      float n45 = fmaf(e4 * e4, s5, e5 * e5 * s4);
      float n67 = fmaf(e6 * e6, s7, e7 * e7 * s6);
      float n0123 = fmaf(n01, s23, n23 * s01);
      float n4567 = fmaf(n45, s67, n67 * s45);
      float num = fmaf(n0123, s4567, n4567 * s0123);
      wd[qi] = fmaf(num, __builtin_amdgcn_rcpf(oct), wd[qi]);
      pr[qi] *= oct;  // deferred log: one v_log_f32 per (q,32d) at the end
    }
    if (more) {
#pragma unroll
      for (int dd = 0; dd < 8; ++dd) kk[dd] = kkn[dd];
    }
  }
  const int k = k0 + lane;
#pragma unroll
  for (int qi = 0; qi < 4; ++qi) {
    int q = q0 + qb + qi;
    SC[(size_t)((h << 9) + q) * 512 + k] =
        -0.5f * (wd[qi] + 0.6931471805599453f * __log2f(pr[qi]));  // partial
  }
}

// ---------- softmax + MFMA PV: paired 8-row groups (p, 63-p) -----------------
__global__ __launch_bounds__(256) void softpv_kernel(const float* __restrict__ SCa,
                                                     const float* __restrict__ SCb,
                                                     const short* __restrict__ VTg,
                                                     short* __restrict__ attn2) {
  const int p = blockIdx.x;       // 0..31
  const int h = blockIdx.y;
  const int g0 = p, g1 = 63 - p;  // 8-row groups
  const int nj0 = (g0 >> 3) + 1;  // causal k-tile count (uniform within group)
  const int nj1 = (g1 >> 3) + 1;
  const int t = threadIdx.x, w = t >> 6, lane = t & 63;
  __shared__ __align__(16) short P2[16][520];   // p bf16, rows 0-7 g0, 8-15 g1
  __shared__ __align__(16) short VT_s[64][72];  // V^T tile [d][k]
  __shared__ float inv_s[16];
#pragma unroll
  for (int gi = 0; gi < 2; ++gi) {
    const int g = gi ? g1 : g0;
    const int nj = gi ? nj1 : nj0;
#pragma unroll
    for (int r = 0; r < 2; ++r) {
      const int row = gi * 8 + w * 2 + r;
      const int q = g * 8 + w * 2 + r;
      float rv[8];
      float m = -3.4e38f;
#pragma unroll
      for (int j = 0; j < 8; ++j)
        if (j < nj) {
          size_t off = (size_t)((h << 9) + q) * 512 + j * 64 + lane;
          float sc = SCa[off] + SCb[off];
          if (j * 64 + lane > q) sc = -1e9f;  // causal mask
          rv[j] = sc;
          m = fmaxf(m, sc);
        }
#pragma unroll
      for (int off = 32; off; off >>= 1) m = fmaxf(m, __shfl_xor(m, off));
      float sum = 0.f;
#pragma unroll
      for (int j = 0; j < 8; ++j) {
        if (j < nj) {
          float pv = __expf(rv[j] - m);
          sum += pv;
          P2[row][j * 64 + lane] = bf16_hi(pv);
        } else if (j < nj1) {
          P2[row][j * 64 + lane] = 0;  // masked tiles of g0 rows
        }
      }
#pragma unroll
      for (int off = 32; off; off >>= 1) sum += __shfl_xor(sum, off);
      if (lane == 0) inv_s[row] = 1.0f / sum;
    }
  }
  // PV: wave w owns output cols [w*16, w*16+16); K loop over nj1 tiles.
  const int fr = lane & 15, kg = (lane >> 4) << 3;
  f32x4 acc = {};
  for (int kt = 0; kt < nj1; ++kt) {
    __syncthreads();  // P2 complete (kt==0) / previous VT_s reads done
    {  // stage VT tile [d][k] bf16 (contiguous rows from VTg)
      int d = t >> 2, i = (t & 3) << 4;
      const short* src = VTg + (size_t)((h << 6) + d) * 512 + (kt << 6) + i;
      *(short8*)&VT_s[d][i] = *(const short8*)src;
      *(short8*)&VT_s[d][i + 8] = *(const short8*)(src + 8);
    }
    __syncthreads();
#pragma unroll
    for (int ks = 0; ks < 64; ks += 32) {
      short8 a = *(const short8*)&P2[fr][(kt << 6) + ks + kg];
      short8 b = *(const short8*)&VT_s[(w << 4) + fr][ks + kg];
      acc = __builtin_amdgcn_mfma_f32_16x16x32_bf16(a, b, acc, 0, 0, 0);
    }
  }
  const int orow = (lane >> 4) << 2;
#pragma unroll
  for (int j = 0; j < 4; ++j) {
    int row = orow + j;
    int q = (row < 8) ? g0 * 8 + row : g1 * 8 + (row - 8);
    attn2[(size_t)q * 512 + (h << 6) + (w << 4) + fr] = bf16_hi(acc[j] * inv_s[row]);
  }
}

// ---------- O projection: 32x32 tiles, 256 blocks (1/CU) ---------------------
// out = attn2(bf16) · wo^T; wo converted in staging. Wave w owns one 16x16
// quadrant (wr=(w>>1)*16, wc=(w&1)*16), single MFMA accumulator.
__global__ __launch_bounds__(256) void gemm_o(const short* __restrict__ A2,
                                              const float* __restrict__ wo,
                                              float* __restrict__ out) {
  __shared__ __align__(16) short Ah[32][72];
  __shared__ __align__(16) short Bh[32][72];
  const int t = threadIdx.x;
  const int bm = blockIdx.y * 32, bn = blockIdx.x * 32;
  const int w = t >> 6, lane = t & 63;
  const int wr = (w >> 1) << 4, wc = (w & 1) << 4;
  const int fr = lane & 15, kg = (lane >> 4) << 3;
  const int r = t >> 3, c8 = (t & 7) << 3;  // 32 rows, 8 threads/row, 8 elems
  f32x4 acc = {};
  for (int kt = 0; kt < 8; ++kt) {
    const int k0 = kt << 6;
    short8 a0 = *(const short8*)(A2 + (size_t)(bm + r) * 512 + k0 + c8);
    float4 bv0 = *(const float4*)(wo + (size_t)(bn + r) * 512 + k0 + c8);
    float4 bv1 = *(const float4*)(wo + (size_t)(bn + r) * 512 + k0 + c8 + 4);
    __syncthreads();
    *(short8*)&Ah[r][c8] = a0;
    *(short4*)&Bh[r][c8] =
        make_short4(bf16_hi(bv0.x), bf16_hi(bv0.y), bf16_hi(bv0.z), bf16_hi(bv0.w));
    *(short4*)&Bh[r][c8 + 4] =
        make_short4(bf16_hi(bv1.x), bf16_hi(bv1.y), bf16_hi(bv1.z), bf16_hi(bv1.w));
    __syncthreads();
#pragma unroll
    for (int ks = 0; ks < 64; ks += 32) {
      short8 a = *(const short8*)&Ah[wr + fr][ks + kg];
      short8 b = *(const short8*)&Bh[wc + fr][ks + kg];
      acc = __builtin_amdgcn_mfma_f32_16x16x32_bf16(a, b, acc, 0, 0, 0);
    }
  }
  const int orow = (lane >> 4) << 2;
#pragma unroll
  for (int j = 0; j < 4; ++j)
    out[(size_t)(bm + wr + orow + j) * 512 + bn + wc + fr] = acc[j];
}

// ------------------------------------------------------------------------------
extern "C" void kernel_launch(void* const* d_in, const int* in_sizes, int n_in,
                              void* d_out, int out_size, void* d_ws, size_t ws_size,
                              hipStream_t stream) {
  const float* X    = (const float*)d_in[0];
  const float* cosp = (const float*)d_in[1];
  const float* sinp = (const float*)d_in[2];
  // d_in[3] = attention_mask (recomputed inline: exact causal 0/-1e9)
  const float* wq   = (const float*)d_in[4];
  const float* wk   = (const float*)d_in[5];
  const float* wv   = (const float*)d_in[6];
  const float* wo   = (const float*)d_in[7];
  float* out = (float*)d_out;

  uint8_t* W = (uint8_t*)d_ws;
  const size_t MB = 1u << 20;
  float* qms   = (float*)(W + 0 * MB);   // [8][512][64][2] 2MB interleaved
  float* kmsT  = (float*)(W + 2 * MB);   // [8][64][512][2] 2MB interleaved
  short* VTg   = (short*)(W + 4 * MB);   // [512 hd][512 s] bf16 0.5MB
  short* attn2 = (short*)(W + 5 * MB);   // [512][512] bf16 0.5MB
  float* SCa   = (float*)(W + 6 * MB);   // [8][512][512] 8MB (d 0..31 partial)
  float* SCb   = (float*)(W + 14 * MB);  // [8][512][512] 8MB (d 32..63 partial)

  proj_gemm<<<dim3(16, 8, 3), 256, 0, stream>>>(X, wq, wk, wv, cosp, sinp,
                                                qms, kmsT, VTg);
  scores_kernel<<<dim3(16, 32, 8), 256, 0, stream>>>(qms, kmsT, SCa, SCb);
  softpv_kernel<<<dim3(32, 8), 256, 0, stream>>>(SCa, SCb, VTg, attn2);
  gemm_o<<<dim3(16, 16), 256, 0, stream>>>(attn2, wo, out);
}

// Round 22
// 61.430 us; speedup vs baseline: 1.2532x; 1.0746x over previous
//
#include <hip/hip_runtime.h>
#include <math.h>

#define S 512
#define NH 8
#define HD 64

typedef short short8 __attribute__((ext_vector_type(8)));
typedef float f32x4 __attribute__((ext_vector_type(4)));

__device__ __forceinline__ short bf16_hi(float x) {
  union { float f; unsigned u; } v; v.f = x;
  unsigned r = v.u + 0x7fffu + ((v.u >> 16) & 1u);
  return (short)(r >> 16);
}
__device__ __forceinline__ float bf16_val(short h) {
  union { float f; unsigned u; } v; v.u = ((unsigned)(unsigned short)h) << 16;
  return v.f;
}
__device__ __forceinline__ float softplus_f(float x) {
  return fmaxf(x, 0.f) + log1pf(__expf(-fabsf(x))) + 1e-4f;
}

// ---------------------------------------------------------------------------
// proj_gemm, 32x64 tiles (640 blocks, 2.5/CU):
//   z=0 -> Q (3-term split-bf16, rope/softplus -> interleaved qms)
//   z=1 -> K (3-term, transposed rope/softplus -> interleaved kmsT)
//   z=2 -> V (1-term, transposed bf16 VT[h*64+d][s] epilogue)
// fp32 inputs converted to (hi|lo) bf16 during LDS staging.
// qms[h][q][d][2] = {mu, sigma};  kmsT[h][d][s][2] = {mu, sigma}
// ---------------------------------------------------------------------------
__global__ __launch_bounds__(256) void proj_gemm(const float* __restrict__ X,
                                                 const float* __restrict__ wq,
                                                 const float* __restrict__ wk,
                                                 const float* __restrict__ wv,
                                                 const float* __restrict__ cosp,
                                                 const float* __restrict__ sinp,
                                                 float* __restrict__ qms,
                                                 float* __restrict__ kmsT,
                                                 short* __restrict__ VTg) {
  const int z = blockIdx.z;
  if (z == 2 && blockIdx.x >= 8) return;
  __shared__ __align__(16) char smem[27648];
  short (*Ah)[72] = (short(*)[72])(smem);            // 32 rows (M)
  short (*Al)[72] = (short(*)[72])(smem + 4608);
  short (*Bh)[72] = (short(*)[72])(smem + 9216);     // 64 rows (N)
  short (*Bl)[72] = (short(*)[72])(smem + 18432);
  float (*Cs)[69]  = (float(*)[69])(smem);           // 32x69 epilogue reuse
  float (*CsC)[69] = (float(*)[69])(smem + 8832);    // cos tile (K path)
  float (*SsC)[69] = (float(*)[69])(smem + 17664);   // sin tile (K path)

  const float* Bsrc = (z == 0) ? wq : (z == 1) ? wk : wv;
  const int t = threadIdx.x;
  const int bm = blockIdx.y * 32, bn = blockIdx.x * 64;
  const int w = t >> 6, lane = t & 63;
  const int wr = (w >> 1) << 4, wc = (w & 1) << 5;   // wave: rows[wr,wr+16) cols[wc,wc+32)
  const int fr = lane & 15, kg = (lane >> 4) << 3;
  const int ra = t >> 3, ca = (t & 7) << 3;          // A staging: 32 rows, 8 floats
  const int rb = t >> 2, cb = (t & 3) << 4;          // B staging: 64 rows, 16 floats
  f32x4 acc0 = {}, acc1 = {};

  for (int kt = 0; kt < 8; ++kt) {
    const int k0 = kt << 6;
    float4 av[2], bv[4];
#pragma unroll
    for (int i = 0; i < 2; ++i)
      av[i] = *(const float4*)(X + (size_t)(bm + ra) * 512 + k0 + ca + i * 4);
#pragma unroll
    for (int i = 0; i < 4; ++i)
      bv[i] = *(const float4*)(Bsrc + (size_t)(bn + rb) * 512 + k0 + cb + i * 4);
    __syncthreads();  // previous step's fragment reads done
#pragma unroll
    for (int i = 0; i < 2; ++i) {
      float fa[4] = {av[i].x, av[i].y, av[i].z, av[i].w};
      short ha[4], la[4];
#pragma unroll
      for (int j = 0; j < 4; ++j) {
        ha[j] = bf16_hi(fa[j]); la[j] = bf16_hi(fa[j] - bf16_val(ha[j]));
      }
      *(short4*)&Ah[ra][ca + i * 4] = make_short4(ha[0], ha[1], ha[2], ha[3]);
      if (z < 2)
        *(short4*)&Al[ra][ca + i * 4] = make_short4(la[0], la[1], la[2], la[3]);
    }
#pragma unroll
    for (int i = 0; i < 4; ++i) {
      float fb[4] = {bv[i].x, bv[i].y, bv[i].z, bv[i].w};
      short hb[4], lb[4];
#pragma unroll
      for (int j = 0; j < 4; ++j) {
        hb[j] = bf16_hi(fb[j]); lb[j] = bf16_hi(fb[j] - bf16_val(hb[j]));
      }
      *(short4*)&Bh[rb][cb + i * 4] = make_short4(hb[0], hb[1], hb[2], hb[3]);
      if (z < 2)
        *(short4*)&Bl[rb][cb + i * 4] = make_short4(lb[0], lb[1], lb[2], lb[3]);
    }
    __syncthreads();
#pragma unroll
    for (int ks = 0; ks < 64; ks += 32) {
      short8 ahf = *(const short8*)&Ah[wr + fr][ks + kg];
      short8 bh0f = *(const short8*)&Bh[wc + fr][ks + kg];
      short8 bh1f = *(const short8*)&Bh[wc + 16 + fr][ks + kg];
      acc0 = __builtin_amdgcn_mfma_f32_16x16x32_bf16(ahf, bh0f, acc0, 0, 0, 0);
      acc1 = __builtin_amdgcn_mfma_f32_16x16x32_bf16(ahf, bh1f, acc1, 0, 0, 0);
      if (z < 2) {
        short8 alf = *(const short8*)&Al[wr + fr][ks + kg];
        short8 bl0f = *(const short8*)&Bl[wc + fr][ks + kg];
        short8 bl1f = *(const short8*)&Bl[wc + 16 + fr][ks + kg];
        acc0 = __builtin_amdgcn_mfma_f32_16x16x32_bf16(alf, bh0f, acc0, 0, 0, 0);
        acc1 = __builtin_amdgcn_mfma_f32_16x16x32_bf16(alf, bh1f, acc1, 0, 0, 0);
        acc0 = __builtin_amdgcn_mfma_f32_16x16x32_bf16(ahf, bl0f, acc0, 0, 0, 0);
        acc1 = __builtin_amdgcn_mfma_f32_16x16x32_bf16(ahf, bl1f, acc1, 0, 0, 0);
      }
    }
  }

  const int orow = (lane >> 4) << 2;
  // ---- epilogue: stage C tile (32x64) in LDS ----
  __syncthreads();  // all fragment reads of staging LDS done
#pragma unroll
  for (int j = 0; j < 4; ++j) {
    Cs[wr + orow + j][wc + fr] = acc0[j];
    Cs[wr + orow + j][wc + 16 + fr] = acc1[j];
  }
  const int h = bn >> 7;
  const int issig = (bn >> 6) & 1;
  if (z == 1 && !issig) {  // stage cos/sin tiles for transposed reads
#pragma unroll
    for (int i = 0; i < 8; ++i) {
      int rr = (i << 2) + w;
      CsC[rr][lane] = cosp[(size_t)(bm + rr) * 64 + lane];
      SsC[rr][lane] = sinp[(size_t)(bm + rr) * 64 + lane];
    }
  }
  __syncthreads();

  if (z == 2) {  // V out: transposed bf16 VT[(bn+d)][bm+sl]
    int d = t >> 2, sl8 = (t & 3) << 3;
#pragma unroll
    for (int i = 0; i < 8; ++i)
      VTg[(size_t)(bn + d) * 512 + bm + sl8 + i] = bf16_hi(Cs[sl8 + i][d]);
    return;
  }
  if (z == 0) {  // Q out: interleaved qms[h][q][d][2]
#pragma unroll
    for (int i = 0; i < 8; ++i) {
      int rr = (i << 2) + w, d = lane, s = bm + rr;
      float c = Cs[rr][d];
      float v;
      if (!issig) {
        float p = Cs[rr][d ^ 32];
        float rot = (d < 32) ? -p : p;
        v = c * cosp[(size_t)s * 64 + d] + rot * sinp[(size_t)s * 64 + d];
      } else {
        v = softplus_f(c);
      }
      qms[(size_t)((h << 9) + s) * 128 + (d << 1) + issig] = v;
    }
  } else {  // K out: interleaved transposed kmsT[h][d][s][2]
    const int sl = lane & 31, dh = (lane >> 5) << 5;
#pragma unroll
    for (int i = 0; i < 8; ++i) {
      int d = (i << 2) + w + dh;
      float c = Cs[sl][d];
      float v;
      if (!issig) {
        float p = Cs[sl][d ^ 32];
        float rot = (d < 32) ? -p : p;
        v = c * CsC[sl][d] + rot * SsC[sl][d];
      } else {
        v = softplus_f(c);
      }
      kmsT[(size_t)((h << 6) + d) * 1024 + ((bm + sl) << 1) + issig] = v;
    }
  }
}

// ---------- W2 scores, split-D, oct-rcp + single deferred log (R19 proven) ---
__global__ __launch_bounds__(256) void scores_kernel(const float* __restrict__ qms,
                                                     const float* __restrict__ kmsT,
                                                     float* __restrict__ SCa,
                                                     float* __restrict__ SCb) {
  const int kt = blockIdx.x >> 1, half = blockIdx.x & 1;
  const int qt = blockIdx.y, h = blockIdx.z;
  const int q0 = qt * 16, k0 = kt * 64;
  if (k0 > q0 + 15) return;  // fully masked tile
  float* __restrict__ SC = half ? SCb : SCa;
  const int dbase = half << 5;
  __shared__ __align__(16) float K_s[32][132];  // [d][2k interleaved], pad 4
  const int t = threadIdx.x, lane = t & 63;
  {  // stage 32 d-rows x 128 floats (64 k's interleaved mu/sig)
    int d = t >> 3, i = t & 7;
    const float* src = kmsT + (size_t)((h << 6) + dbase + d) * 1024 + (k0 << 1) + i * 16;
    float* dst = &K_s[d][i * 16];
#pragma unroll
    for (int j = 0; j < 4; ++j)
      *(float4*)(dst + j * 4) = *(const float4*)(src + j * 4);
  }
  __syncthreads();
  const int qb = __builtin_amdgcn_readfirstlane((t >> 6) << 2);  // wave's 4 q rows
  const float* __restrict__ qp = qms + (size_t)((h << 9) + q0 + qb) * 128 + (dbase << 1);
  float wd[4] = {}, pr[4] = {1.f, 1.f, 1.f, 1.f};
  float2 kk[8], kkn[8];
#pragma unroll
  for (int dd = 0; dd < 8; ++dd)
    kk[dd] = *(const float2*)&K_s[dd][lane << 1];
  for (int d0 = 0; d0 < 32; d0 += 8) {
    const bool more = (d0 < 24);
    if (more) {
#pragma unroll
      for (int dd = 0; dd < 8; ++dd)
        kkn[dd] = *(const float2*)&K_s[d0 + 8 + dd][lane << 1];
    }
#pragma unroll
    for (int qi = 0; qi < 4; ++qi) {
      float qv[16];
      const float* qq = qp + qi * 128 + (d0 << 1);
#pragma unroll
      for (int j = 0; j < 4; ++j)
        *(float4*)&qv[j * 4] = *(const float4*)(qq + j * 4);
      float s0 = qv[1]  + kk[0].y, s1 = qv[3]  + kk[1].y;
      float s2 = qv[5]  + kk[2].y, s3 = qv[7]  + kk[3].y;
      float s4 = qv[9]  + kk[4].y, s5 = qv[11] + kk[5].y;
      float s6 = qv[13] + kk[6].y, s7 = qv[15] + kk[7].y;
      float e0 = qv[0]  - kk[0].x, e1 = qv[2]  - kk[1].x;
      float e2 = qv[4]  - kk[2].x, e3 = qv[6]  - kk[3].x;
      float e4 = qv[8]  - kk[4].x, e5 = qv[10] - kk[5].x;
      float e6 = qv[12] - kk[6].x, e7 = qv[14] - kk[7].x;
      float s01 = s0 * s1, s23 = s2 * s3, s45 = s4 * s5, s67 = s6 * s7;
      float s0123 = s01 * s23, s4567 = s45 * s67;
      float oct = s0123 * s4567;
      float n01 = fmaf(e0 * e0, s1, e1 * e1 * s0);
      float n23 = fmaf(e2 * e2, s3, e3 * e3 * s2);
      float n45 = fmaf(e4 * e4, s5, e5 * e5 * s4);
      float n67 = fmaf(e6 * e6, s7, e7 * e7 * s6);
      float n0123 = fmaf(n01, s23, n23 * s01);
      float n4567 = fmaf(n45, s67, n67 * s45);
      float num = fmaf(n0123, s4567, n4567 * s0123);
      wd[qi] = fmaf(num, __builtin_amdgcn_rcpf(oct), wd[qi]);
      pr[qi] *= oct;  // deferred log: one v_log_f32 per (q,32d) at the end
    }
    if (more) {
#pragma unroll
      for (int dd = 0; dd < 8; ++dd) kk[dd] = kkn[dd];
    }
  }
  const int k = k0 + lane;
#pragma unroll
  for (int qi = 0; qi < 4; ++qi) {
    int q = q0 + qb + qi;
    SC[(size_t)((h << 9) + q) * 512 + k] =
        -0.5f * (wd[qi] + 0.6931471805599453f * __log2f(pr[qi]));  // partial
  }
}

// ---------- softmax + MFMA PV: paired 8-row groups (p, 63-p) -----------------
__global__ __launch_bounds__(256) void softpv_kernel(const float* __restrict__ SCa,
                                                     const float* __restrict__ SCb,
                                                     const short* __restrict__ VTg,
                                                     short* __restrict__ attn2) {
  const int p = blockIdx.x;       // 0..31
  const int h = blockIdx.y;
  const int g0 = p, g1 = 63 - p;  // 8-row groups
  const int nj0 = (g0 >> 3) + 1;  // causal k-tile count (uniform within group)
  const int nj1 = (g1 >> 3) + 1;
  const int t = threadIdx.x, w = t >> 6, lane = t & 63;
  __shared__ __align__(16) short P2[16][520];   // p bf16, rows 0-7 g0, 8-15 g1
  __shared__ __align__(16) short VT_s[64][72];  // V^T tile [d][k]
  __shared__ float inv_s[16];
#pragma unroll
  for (int gi = 0; gi < 2; ++gi) {
    const int g = gi ? g1 : g0;
    const int nj = gi ? nj1 : nj0;
#pragma unroll
    for (int r = 0; r < 2; ++r) {
      const int row = gi * 8 + w * 2 + r;
      const int q = g * 8 + w * 2 + r;
      float rv[8];
      float m = -3.4e38f;
#pragma unroll
      for (int j = 0; j < 8; ++j)
        if (j < nj) {
          size_t off = (size_t)((h << 9) + q) * 512 + j * 64 + lane;
          float sc = SCa[off] + SCb[off];
          if (j * 64 + lane > q) sc = -1e9f;  // causal mask
          rv[j] = sc;
          m = fmaxf(m, sc);
        }
#pragma unroll
      for (int off = 32; off; off >>= 1) m = fmaxf(m, __shfl_xor(m, off));
      float sum = 0.f;
#pragma unroll
      for (int j = 0; j < 8; ++j) {
        if (j < nj) {
          float pv = __expf(rv[j] - m);
          sum += pv;
          P2[row][j * 64 + lane] = bf16_hi(pv);
        } else if (j < nj1) {
          P2[row][j * 64 + lane] = 0;  // masked tiles of g0 rows
        }
      }
#pragma unroll
      for (int off = 32; off; off >>= 1) sum += __shfl_xor(sum, off);
      if (lane == 0) inv_s[row] = 1.0f / sum;
    }
  }
  // PV: wave w owns output cols [w*16, w*16+16); K loop over nj1 tiles.
  const int fr = lane & 15, kg = (lane >> 4) << 3;
  f32x4 acc = {};
  for (int kt = 0; kt < nj1; ++kt) {
    __syncthreads();  // P2 complete (kt==0) / previous VT_s reads done
    {  // stage VT tile [d][k] bf16 (contiguous rows from VTg)
      int d = t >> 2, i = (t & 3) << 4;
      const short* src = VTg + (size_t)((h << 6) + d) * 512 + (kt << 6) + i;
      *(short8*)&VT_s[d][i] = *(const short8*)src;
      *(short8*)&VT_s[d][i + 8] = *(const short8*)(src + 8);
    }
    __syncthreads();
#pragma unroll
    for (int ks = 0; ks < 64; ks += 32) {
      short8 a = *(const short8*)&P2[fr][(kt << 6) + ks + kg];
      short8 b = *(const short8*)&VT_s[(w << 4) + fr][ks + kg];
      acc = __builtin_amdgcn_mfma_f32_16x16x32_bf16(a, b, acc, 0, 0, 0);
    }
  }
  const int orow = (lane >> 4) << 2;
#pragma unroll
  for (int j = 0; j < 4; ++j) {
    int row = orow + j;
    int q = (row < 8) ? g0 * 8 + row : g1 * 8 + (row - 8);
    attn2[(size_t)q * 512 + (h << 6) + (w << 4) + fr] = bf16_hi(acc[j] * inv_s[row]);
  }
}

// ---------- O projection: 32x32 tiles, 256 blocks (1/CU), R21 proven ---------
__global__ __launch_bounds__(256) void gemm_o(const short* __restrict__ A2,
                                              const float* __restrict__ wo,
                                              float* __restrict__ out) {
  __shared__ __align__(16) short Ah[32][72];
  __shared__ __align__(16) short Bh[32][72];
  const int t = threadIdx.x;
  const int bm = blockIdx.y * 32, bn = blockIdx.x * 32;
  const int w = t >> 6, lane = t & 63;
  const int wr = (w >> 1) << 4, wc = (w & 1) << 4;
  const int fr = lane & 15, kg = (lane >> 4) << 3;
  const int r = t >> 3, c8 = (t & 7) << 3;  // 32 rows, 8 threads/row, 8 elems
  f32x4 acc = {};
  for (int kt = 0; kt < 8; ++kt) {
    const int k0 = kt << 6;
    short8 a0 = *(const short8*)(A2 + (size_t)(bm + r) * 512 + k0 + c8);
    float4 bv0 = *(const float4*)(wo + (size_t)(bn + r) * 512 + k0 + c8);
    float4 bv1 = *(const float4*)(wo + (size_t)(bn + r) * 512 + k0 + c8 + 4);
    __syncthreads();
    *(short8*)&Ah[r][c8] = a0;
    *(short4*)&Bh[r][c8] =
        make_short4(bf16_hi(bv0.x), bf16_hi(bv0.y), bf16_hi(bv0.z), bf16_hi(bv0.w));
    *(short4*)&Bh[r][c8 + 4] =
        make_short4(bf16_hi(bv1.x), bf16_hi(bv1.y), bf16_hi(bv1.z), bf16_hi(bv1.w));
    __syncthreads();
#pragma unroll
    for (int ks = 0; ks < 64; ks += 32) {
      short8 a = *(const short8*)&Ah[wr + fr][ks + kg];
      short8 b = *(const short8*)&Bh[wc + fr][ks + kg];
      acc = __builtin_amdgcn_mfma_f32_16x16x32_bf16(a, b, acc, 0, 0, 0);
    }
  }
  const int orow = (lane >> 4) << 2;
#pragma unroll
  for (int j = 0; j < 4; ++j)
    out[(size_t)(bm + wr + orow + j) * 512 + bn + wc + fr] = acc[j];
}

// ------------------------------------------------------------------------------
extern "C" void kernel_launch(void* const* d_in, const int* in_sizes, int n_in,
                              void* d_out, int out_size, void* d_ws, size_t ws_size,
                              hipStream_t stream) {
  const float* X    = (const float*)d_in[0];
  const float* cosp = (const float*)d_in[1];
  const float* sinp = (const float*)d_in[2];
  // d_in[3] = attention_mask (recomputed inline: exact causal 0/-1e9)
  const float* wq   = (const float*)d_in[4];
  const float* wk   = (const float*)d_in[5];
  const float* wv   = (const float*)d_in[6];
  const float* wo   = (const float*)d_in[7];
  float* out = (float*)d_out;

  uint8_t* W = (uint8_t*)d_ws;
  const size_t MB = 1u << 20;
  float* qms   = (float*)(W + 0 * MB);   // [8][512][64][2] 2MB interleaved
  float* kmsT  = (float*)(W + 2 * MB);   // [8][64][512][2] 2MB interleaved
  short* VTg   = (short*)(W + 4 * MB);   // [512 hd][512 s] bf16 0.5MB
  short* attn2 = (short*)(W + 5 * MB);   // [512][512] bf16 0.5MB
  float* SCa   = (float*)(W + 6 * MB);   // [8][512][512] 8MB (d 0..31 partial)
  float* SCb   = (float*)(W + 14 * MB);  // [8][512][512] 8MB (d 32..63 partial)

  proj_gemm<<<dim3(16, 16, 3), 256, 0, stream>>>(X, wq, wk, wv, cosp, sinp,
                                                 qms, kmsT, VTg);
  scores_kernel<<<dim3(16, 32, 8), 256, 0, stream>>>(qms, kmsT, SCa, SCb);
  softpv_kernel<<<dim3(32, 8), 256, 0, stream>>>(SCa, SCb, VTg, attn2);
  gemm_o<<<dim3(16, 16), 256, 0, stream>>>(attn2, wo, out);
}